// Round 11
// baseline (30.280 us; speedup 1.0000x reference)
//
#include <hip/hip_runtime.h>
#include <math.h>

#define BLK    256
#define SRCB   32      // src points per block (4 waves x 8 per thread)
#define SPT    8       // src points per thread
#define TILE   512     // target points per LDS tile (8 KB)
#define NT     4       // target chunks (grid dim y)
#define NRB    32      // reduce blocks per direction

// pack: p[i] = {x, y, z, 0.5*|p|^2}
__global__ void hd_pack_kernel(const float* __restrict__ s1, int n1,
                               const float* __restrict__ s2, int n2,
                               float4* __restrict__ p1, float4* __restrict__ p2) {
    const int i = blockIdx.x * BLK + threadIdx.x;
    if (i < n1) {
        float x = s1[3 * i], y = s1[3 * i + 1], z = s1[3 * i + 2];
        p1[i] = make_float4(x, y, z, 0.5f * fmaf(z, z, fmaf(y, y, x * x)));
    }
    if (i < n2) {
        float x = s2[3 * i], y = s2[3 * i + 1], z = s2[3 * i + 2];
        p2[i] = make_float4(x, y, z, 0.5f * fmaf(z, z, fmaf(y, y, x * x)));
    }
}

// grid (nbx, NT, 2). Block: SRCB src points vs one target chunk.
// Wave w owns src octet; all 64 lanes hold the SAME 8 src points and cover
// disjoint targets (lane-strided), finishing with an in-wave shfl butterfly.
// Writes per-src chunk-min d^2 to pmin[dir][chunk][i]. No atomics.
// min_t |s-t|^2 = 2*(0.5|s|^2 + min_t(0.5|t|^2 - s.t)); negated src makes the
// inner term fma(t.x,sx, fma(t.y,sy, fma(t.z,sz, t.w))) -> 3 FMA + 1 min/pair.
__global__ void __launch_bounds__(BLK, 4)
hd_min_kernel(const float4* __restrict__ p1, int n1,
              const float4* __restrict__ p2, int n2,
              float* __restrict__ pmin, int maxN) {
    const int dir = blockIdx.z;
    const float4* src = dir ? p2 : p1;
    const float4* tgt = dir ? p1 : p2;
    const int nSrc    = dir ? n2 : n1;
    const int nTgt    = dir ? n1 : n2;

    if (blockIdx.x * SRCB >= nSrc) return;     // uniform

    const int w    = threadIdx.x >> 6;
    const int lane = threadIdx.x & 63;
    const int base = blockIdx.x * SRCB + w * SPT;

    const int chunkLen = (nTgt + NT - 1) / NT;
    const int cbeg = blockIdx.y * chunkLen;
    const int cend = min(cbeg + chunkLen, nTgt);

    // SPT src points in registers (negated xyz; keep 0.5|s|^2)
    float sx[SPT], sy[SPT], sz[SPT], sw[SPT];
    #pragma unroll
    for (int k = 0; k < SPT; ++k) {
        const int i = base + k;
        float4 s = (i < nSrc) ? src[i] : make_float4(0.f, 0.f, 0.f, 0.f);
        sx[k] = -s.x; sy[k] = -s.y; sz[k] = -s.z; sw[k] = s.w;
    }
    float m[SPT];
    #pragma unroll
    for (int k = 0; k < SPT; ++k) m[k] = INFINITY;

    __shared__ float4 ldsT[TILE];

    for (int tile = cbeg; tile < cend; tile += TILE) {
        // stage full TILE (coalesced float4); pad w=+inf (never wins the min)
        #pragma unroll
        for (int r = 0; r < TILE / BLK; ++r) {
            const int idx = r * BLK + threadIdx.x;
            const int j = tile + idx;
            ldsT[idx] = (j < cend) ? tgt[j]
                                   : make_float4(0.f, 0.f, 0.f, INFINITY);
        }
        __syncthreads();

        #pragma unroll
        for (int c = 0; c < TILE / 64; ++c) {
            const float4 t = ldsT[c * 64 + lane];   // consecutive b128, conflict-free
            #pragma unroll
            for (int k = 0; k < SPT; ++k) {
                const float v = fmaf(t.x, sx[k], fmaf(t.y, sy[k], fmaf(t.z, sz[k], t.w)));
                m[k] = fminf(m[k], v);
            }
        }
        __syncthreads();
    }

    // in-wave butterfly min
    #pragma unroll
    for (int off = 1; off < 64; off <<= 1) {
        #pragma unroll
        for (int k = 0; k < SPT; ++k)
            m[k] = fminf(m[k], __shfl_xor(m[k], off));
    }

    // lane 0 writes the 8 chunk-min d^2 values (static indexing, no scratch)
    if (lane == 0) {
        float* dst = pmin + ((size_t)dir * NT + blockIdx.y) * (size_t)maxN + base;
        #pragma unroll
        for (int k = 0; k < SPT; ++k) {
            if (base + k < nSrc)
                dst[k] = fmaxf(2.0f * (m[k] + sw[k]), 0.0f);
        }
    }
}

// grid (NRB, 2): min over NT chunks -> sqrt -> per-block {sum, max} partial.
__global__ void hd_reduce_kernel(const float* __restrict__ pmin, int maxN,
                                 int n1, int n2, float2* __restrict__ bpart) {
    const int dir = blockIdx.y;
    const int n = dir ? n2 : n1;
    const float* pm = pmin + (size_t)dir * NT * maxN;

    float sum = 0.f, mx = 0.f;
    for (int i = blockIdx.x * BLK + threadIdx.x; i < n; i += NRB * BLK) {
        const float v0 = pm[i];
        const float v1 = pm[(size_t)maxN + i];
        const float v2 = pm[2 * (size_t)maxN + i];
        const float v3 = pm[3 * (size_t)maxN + i];
        const float d = sqrtf(fminf(fminf(v0, v1), fminf(v2, v3)));
        sum += d;
        mx = fmaxf(mx, d);
    }
    for (int o = 32; o > 0; o >>= 1) {
        sum += __shfl_down(sum, o);
        mx = fmaxf(mx, __shfl_down(mx, o));
    }
    __shared__ float ssum[BLK / 64], smax[BLK / 64];
    const int w = threadIdx.x >> 6, lane = threadIdx.x & 63;
    if (lane == 0) { ssum[w] = sum; smax[w] = mx; }
    __syncthreads();
    if (threadIdx.x == 0) {
        float s = 0.f, mm = 0.f;
        #pragma unroll
        for (int q = 0; q < BLK / 64; ++q) { s += ssum[q]; mm = fmaxf(mm, smax[q]); }
        bpart[dir * NRB + blockIdx.x] = make_float2(s, mm);
    }
}

// single wave: combine 2*NRB partials + flag logic
__global__ void hd_final_kernel(const float2* __restrict__ bpart,
                                int n1, int n2,
                                const int* __restrict__ haus,
                                const int* __restrict__ w12,
                                const int* __restrict__ w21,
                                const int* __restrict__ nout,
                                float* __restrict__ out) {
    const int t = threadIdx.x;   // 64 threads
    float s0 = 0.f, x0 = 0.f, s1 = 0.f, x1 = 0.f;
    if (t < NRB) {
        const float2 a = bpart[t];
        const float2 b = bpart[NRB + t];
        s0 = a.x; x0 = a.y; s1 = b.x; x1 = b.y;
    }
    for (int o = 32; o > 0; o >>= 1) {
        s0 += __shfl_down(s0, o); x0 = fmaxf(x0, __shfl_down(x0, o));
        s1 += __shfl_down(s1, o); x1 = fmaxf(x1, __shfl_down(x1, o));
    }
    if (t == 0) {
        float t12 = 0.f, t21 = 0.f;
        if (*w12 != 0) t12 = (*haus == 0) ? s0 / (float)n1 : x0;
        if (*w21 != 0) t21 = (*haus == 0) ? s1 / (float)n2 : x1;
        if (*nout == 1) {
            out[0] = t12 + t21;
        } else {
            out[0] = t12;
            out[1] = t21;
        }
    }
}

extern "C" void kernel_launch(void* const* d_in, const int* in_sizes, int n_in,
                              void* d_out, int out_size, void* d_ws, size_t ws_size,
                              hipStream_t stream) {
    const float* s1 = (const float*)d_in[0];
    const float* s2 = (const float*)d_in[1];
    const int* haus = (const int*)d_in[2];
    const int* w12  = (const int*)d_in[3];
    const int* w21  = (const int*)d_in[4];
    const int* nout = (const int*)d_in[5];
    float* out = (float*)d_out;

    const int n1 = in_sizes[0] / 3;
    const int n2 = in_sizes[1] / 3;
    const int maxN = (n1 > n2) ? n1 : n2;
    const int nbx = (maxN + SRCB - 1) / SRCB;

    // ws: p1[n1] f4 | p2[n2] f4 | pmin[2][NT][maxN] f32 | bpart[2][NRB] f2
    float4* p1 = (float4*)d_ws;
    float4* p2 = p1 + n1;
    float* pmin = (float*)(p2 + n2);
    float2* bpart = (float2*)(pmin + (size_t)2 * NT * maxN);

    hd_pack_kernel<<<(maxN + BLK - 1) / BLK, BLK, 0, stream>>>(s1, n1, s2, n2, p1, p2);

    dim3 grid(nbx, NT, 2);
    hd_min_kernel<<<grid, BLK, 0, stream>>>(p1, n1, p2, n2, pmin, maxN);

    hd_reduce_kernel<<<dim3(NRB, 2), BLK, 0, stream>>>(pmin, maxN, n1, n2, bpart);

    hd_final_kernel<<<1, 64, 0, stream>>>(bpart, n1, n2, haus, w12, w21, nout, out);
}

// Round 13
// 27.163 us; speedup vs baseline: 1.1148x; 1.1148x over previous
//
#include <hip/hip_runtime.h>
#include <math.h>

#define BLK    256
#define SRCB   32      // src points per block (4 waves x 8 per thread)
#define SPT    8       // src points per thread
#define TILE   512     // target points per LDS tile (2 x 4KB pair-SoA)

typedef float v2f __attribute__((ext_vector_type(2)));
typedef float v4f __attribute__((ext_vector_type(4)));

// Each block: SRCB src points (one direction) vs ALL targets; no atomics.
// Targets staged pair-SoA in SCALAR float LDS (element-wise ds_write_b32 --
// no vector RMW race): pair p occupies ldsA[4p..4p+3]={x0,x1,y0,y1},
// ldsB[4p..4p+3]={z0,z1,w0,w1} (w = 0.5|t|^2). Compute reads them back as
// aligned v4f (ds_read_b128, consecutive per lane, conflict-free).
// Inner math per 2 targets per src (packed fp32 v_pk_fma_f32):
//   v01 = pk_fma(x01, -sx, pk_fma(y01, -sy, pk_fma(z01, -sz, w01)))
//   m   = min3(m, v01.x, v01.y)            -> 2 VALU per pair.
// min_t |s-t|^2 = 2*(0.5|s|^2 + min v). All 64 lanes of a wave hold the SAME
// 8 src points, cover disjoint targets; finish with an in-wave shfl butterfly;
// block writes one {sum sqrt, max sqrt} partial. No atomics anywhere.
__global__ void __launch_bounds__(BLK, 2)
hd_min_kernel(const float* __restrict__ s1, int n1,
              const float* __restrict__ s2, int n2,
              float2* __restrict__ bpart, int nbx) {
    const int dir = blockIdx.y;
    const float* src = dir ? s2 : s1;
    const float* tgt = dir ? s1 : s2;
    const int nSrc   = dir ? n2 : n1;
    const int nTgt   = dir ? n1 : n2;

    if (blockIdx.x * SRCB >= nSrc) {           // uniform; keep bpart defined
        if (threadIdx.x == 0) bpart[dir * nbx + blockIdx.x] = make_float2(0.f, 0.f);
        return;
    }

    const int w    = threadIdx.x >> 6;
    const int lane = threadIdx.x & 63;
    const int base = blockIdx.x * SRCB + w * SPT;

    // SPT src points: negated coords splatted to v2f; keep 0.5|s|^2 scalar
    v2f sx2[SPT], sy2[SPT], sz2[SPT];
    float swq[SPT], m[SPT];
    #pragma unroll
    for (int k = 0; k < SPT; ++k) {
        const int i = base + k;
        float x = 0.f, y = 0.f, z = 0.f;
        if (i < nSrc) { x = src[3*i]; y = src[3*i+1]; z = src[3*i+2]; }
        sx2[k] = -x; sy2[k] = -y; sz2[k] = -z;          // scalar -> v2f splat
        swq[k] = 0.5f * fmaf(z, z, fmaf(y, y, x * x));
        m[k] = INFINITY;
    }

    __shared__ alignas(16) float ldsA[TILE * 2];   // pair p: {x0,x1,y0,y1}
    __shared__ alignas(16) float ldsB[TILE * 2];   // pair p: {z0,z1,w0,w1}

    for (int tile = 0; tile < nTgt; tile += TILE) {
        #pragma unroll
        for (int r = 0; r < TILE / BLK; ++r) {
            const int idx = r * BLK + threadIdx.x;
            const int j = tile + idx;
            float x = 0.f, y = 0.f, z = 0.f, tw = INFINITY;  // pad never wins min
            if (j < nTgt) {
                x = tgt[3*j]; y = tgt[3*j+1]; z = tgt[3*j+2];
                tw = 0.5f * fmaf(z, z, fmaf(y, y, x * x));
            }
            const int p4 = (idx >> 1) << 2, sl = idx & 1;
            ldsA[p4 + sl]     = x;      // scalar ds_write_b32 -- no RMW race
            ldsA[p4 + 2 + sl] = y;
            ldsB[p4 + sl]     = z;
            ldsB[p4 + 2 + sl] = tw;
        }
        __syncthreads();

        #pragma unroll
        for (int q = 0; q < TILE / 2 / 64; ++q) {   // 4 pairs per lane per tile
            const int p4 = (q * 64 + lane) << 2;
            const v4f A = *reinterpret_cast<const v4f*>(&ldsA[p4]);  // b128
            const v4f B = *reinterpret_cast<const v4f*>(&ldsB[p4]);
            const v2f x01 = A.xy, y01 = A.zw, z01 = B.xy, w01 = B.zw;
            #pragma unroll
            for (int k = 0; k < SPT; ++k) {
                const v2f v = __builtin_elementwise_fma(x01, sx2[k],
                              __builtin_elementwise_fma(y01, sy2[k],
                              __builtin_elementwise_fma(z01, sz2[k], w01)));
                m[k] = fminf(fminf(m[k], v.x), v.y);   // -> v_min3_f32
            }
        }
        __syncthreads();
    }

    // in-wave butterfly min: all lanes end with the full-target min per k
    #pragma unroll
    for (int off = 1; off < 64; off <<= 1) {
        #pragma unroll
        for (int k = 0; k < SPT; ++k)
            m[k] = fminf(m[k], __shfl_xor(m[k], off));
    }

    // per-wave {sum sqrt, max sqrt}; block combine; plain store
    __shared__ float ssum[BLK / 64], smax[BLK / 64];
    if (lane == 0) {
        float sum = 0.f, mx = 0.f;
        #pragma unroll
        for (int k = 0; k < SPT; ++k) {
            if (base + k < nSrc) {
                const float d = sqrtf(fmaxf(2.0f * (m[k] + swq[k]), 0.0f));
                sum += d;
                mx = fmaxf(mx, d);
            }
        }
        ssum[w] = sum; smax[w] = mx;
    }
    __syncthreads();
    if (threadIdx.x == 0) {
        float s = 0.f, mm = 0.f;
        #pragma unroll
        for (int q = 0; q < BLK / 64; ++q) { s += ssum[q]; mm = fmaxf(mm, smax[q]); }
        bpart[dir * nbx + blockIdx.x] = make_float2(s, mm);
    }
}

// Single block: reduce per-block partials for both directions + flag logic.
__global__ void hd_final_kernel(const float2* __restrict__ bpart, int nbx,
                                int n1, int n2,
                                const int* __restrict__ haus,
                                const int* __restrict__ w12,
                                const int* __restrict__ w21,
                                const int* __restrict__ nout,
                                float* __restrict__ out) {
    float s0 = 0.f, x0 = 0.f, s1 = 0.f, x1 = 0.f;
    for (int t = threadIdx.x; t < nbx; t += BLK) {
        const float2 a = bpart[t];
        const float2 b = bpart[nbx + t];
        s0 += a.x; x0 = fmaxf(x0, a.y);
        s1 += b.x; x1 = fmaxf(x1, b.y);
    }
    for (int o = 32; o > 0; o >>= 1) {
        s0 += __shfl_down(s0, o); x0 = fmaxf(x0, __shfl_down(x0, o));
        s1 += __shfl_down(s1, o); x1 = fmaxf(x1, __shfl_down(x1, o));
    }
    __shared__ float a0[BLK/64], b0[BLK/64], a1[BLK/64], b1[BLK/64];
    const int w = threadIdx.x >> 6, lane = threadIdx.x & 63;
    if (lane == 0) { a0[w] = s0; b0[w] = x0; a1[w] = s1; b1[w] = x1; }
    __syncthreads();
    if (threadIdx.x == 0) {
        float S0 = 0.f, X0 = 0.f, S1 = 0.f, X1 = 0.f;
        for (int q = 0; q < BLK/64; ++q) {
            S0 += a0[q]; X0 = fmaxf(X0, b0[q]);
            S1 += a1[q]; X1 = fmaxf(X1, b1[q]);
        }
        float t12 = 0.f, t21 = 0.f;
        if (*w12 != 0) t12 = (*haus == 0) ? S0 / (float)n1 : X0;
        if (*w21 != 0) t21 = (*haus == 0) ? S1 / (float)n2 : X1;
        if (*nout == 1) {
            out[0] = t12 + t21;
        } else {
            out[0] = t12;
            out[1] = t21;
        }
    }
}

extern "C" void kernel_launch(void* const* d_in, const int* in_sizes, int n_in,
                              void* d_out, int out_size, void* d_ws, size_t ws_size,
                              hipStream_t stream) {
    const float* s1 = (const float*)d_in[0];
    const float* s2 = (const float*)d_in[1];
    const int* haus = (const int*)d_in[2];
    const int* w12  = (const int*)d_in[3];
    const int* w21  = (const int*)d_in[4];
    const int* nout = (const int*)d_in[5];
    float* out = (float*)d_out;

    const int n1 = in_sizes[0] / 3;
    const int n2 = in_sizes[1] / 3;
    const int maxN = (n1 > n2) ? n1 : n2;
    const int nbx = (maxN + SRCB - 1) / SRCB;

    float2* bpart = (float2*)d_ws;   // [2][nbx] {sum, max} partials

    dim3 grid(nbx, 2);
    hd_min_kernel<<<grid, BLK, 0, stream>>>(s1, n1, s2, n2, bpart, nbx);

    hd_final_kernel<<<1, BLK, 0, stream>>>(bpart, nbx, n1, n2,
                                           haus, w12, w21, nout, out);
}